// Round 2
// baseline (227.066 us; speedup 1.0000x reference)
//
#include <hip/hip_runtime.h>
#include <math.h>

// x, x_r: (1, 3, 32, 512, 512) fp32. size=64 -> hc=wc=32, nh=nw=16.
// P[t,ph,pw] = mean over (c=3, 32x32) of |x - x_r|/2   (3072 elems/patch)
// out = log( mean_t( max(0, max_{ph,pw} P) ) )  -- scalar fp32.
//
// Round 10: single fused kernel. Round-9 showed the read stream is NOT
//   occupancy-limited (32 waves/CU == 16 waves/CU) -> miss-path capped.
//   Keep the measured-best round-8 stream shape (48 nt dwordx4 loads per
//   thread, 6 independent contiguous streams per block, 16 waves/CU) but
//   make block b own ALL of patch-row (t=b>>4, ph=b&15): 32 rows x 3 ch
//   = 6 segments of 4096 f4 (64 KB) per input. Block reduces its 16 pw
//   patches internally, writes ONE float (its max patch value), and the
//   LAST block (device-global atomic counter, modulo-512 so no reset
//   store is needed across graph replays) runs the 512->scalar finalize.
//   Kills: finalize dispatch (~4 us), one launch gap, 48 KB part round-trip.
// Cross-block visibility: bm[] stores + counter are agent-scope atomics
//   with __threadfence() release/acquire (cross-XCD safe per G16).

typedef float vf4 __attribute__((ext_vector_type(4)));

__device__ int g_count = 0;   // zero-init at module load; never reset:
                              // each launch adds exactly 512, test (old&511)==511

__global__ __launch_bounds__(512, 4) void patch_loss_kernel(
    const float* __restrict__ x, const float* __restrict__ xr,
    float* __restrict__ bm, float* __restrict__ out) {
  const int b   = blockIdx.x;   // 0..511 : t = b>>4, ph = b&15
  const int tid = threadIdx.x;  // 0..511
  const int t  = b >> 4;
  const int ph = b & 15;
  // segment base (f4 units) for channel ch: (ch*32 + t)*65536 + ph*4096
  const size_t s0 = ((size_t)(t)      << 16) + ((size_t)ph << 12);
  const size_t s1 = ((size_t)(32 + t) << 16) + ((size_t)ph << 12);
  const size_t s2 = ((size_t)(64 + t) << 16) + ((size_t)ph << 12);
  const vf4* __restrict__ a4 = (const vf4*)x;
  const vf4* __restrict__ c4 = (const vf4*)xr;

  float acc0 = 0.f, acc1 = 0.f, acc2 = 0.f;
#pragma unroll
  for (int i = 0; i < 8; ++i) {
    int o = i * 512 + tid;             // 0..4095 within each segment
    vf4 A0 = __builtin_nontemporal_load(&a4[s0 + o]);
    vf4 C0 = __builtin_nontemporal_load(&c4[s0 + o]);
    vf4 A1 = __builtin_nontemporal_load(&a4[s1 + o]);
    vf4 C1 = __builtin_nontemporal_load(&c4[s1 + o]);
    vf4 A2 = __builtin_nontemporal_load(&a4[s2 + o]);
    vf4 C2 = __builtin_nontemporal_load(&c4[s2 + o]);
    acc0 += fabsf(A0.x - C0.x) + fabsf(A0.y - C0.y)
          + fabsf(A0.z - C0.z) + fabsf(A0.w - C0.w);
    acc1 += fabsf(A1.x - C1.x) + fabsf(A1.y - C1.y)
          + fabsf(A1.z - C1.z) + fabsf(A1.w - C1.w);
    acc2 += fabsf(A2.x - C2.x) + fabsf(A2.y - C2.y)
          + fabsf(A2.z - C2.z) + fabsf(A2.w - C2.w);
  }
  // col4 = (i*512+tid)&127 = tid&127  ->  pw bin = (tid&127)>>3, constant.
  float acc = acc0 + acc1 + acc2;      // sum over the 3 channels
#pragma unroll
  for (int o = 4; o > 0; o >>= 1) acc += __shfl_down(acc, o, 8);

  __shared__ float sp[16][4];          // [pw][128-thread group]
  if ((tid & 7) == 0) sp[(tid >> 3) & 15][tid >> 7] = acc;
  __syncthreads();

  float bmax = 0.f;
  if (tid < 16) {
    float v = sp[tid][0] + sp[tid][1] + sp[tid][2] + sp[tid][3];
#pragma unroll
    for (int o = 8; o > 0; o >>= 1) v = fmaxf(v, __shfl_down(v, o, 16));
    bmax = v;                          // max over the block's 16 pw patches
  }

  __shared__ int is_last;
  if (tid == 0) {
    __hip_atomic_store(&bm[b], bmax * (0.5f / 3072.0f),
                       __ATOMIC_RELAXED, __HIP_MEMORY_SCOPE_AGENT);
    __threadfence();                   // release bm[b] (device scope)
    int old = __hip_atomic_fetch_add(&g_count, 1, __ATOMIC_ACQ_REL,
                                     __HIP_MEMORY_SCOPE_AGENT);
    is_last = ((old & 511) == 511);
  }
  __syncthreads();
  if (!is_last) return;

  // ---- last block: finalize over 512 (t,ph) maxima ----
  __threadfence();                     // acquire
  float v = __hip_atomic_load(&bm[tid], __ATOMIC_RELAXED,
                              __HIP_MEMORY_SCOPE_AGENT);
#pragma unroll
  for (int o = 8; o > 0; o >>= 1) v = fmaxf(v, __shfl_down(v, o, 16));
  __shared__ float st[32];
  if ((tid & 15) == 0) st[tid >> 4] = fmaxf(v, 0.f);  // frame max, clamp 0
  __syncthreads();
  if (tid < 32) {
    float s = st[tid];
#pragma unroll
    for (int o = 16; o > 0; o >>= 1) s += __shfl_down(s, o, 32);
    if (tid == 0) out[0] = logf(s * (1.0f / 32.0f));
  }
}

extern "C" void kernel_launch(void* const* d_in, const int* in_sizes, int n_in,
                              void* d_out, int out_size, void* d_ws, size_t ws_size,
                              hipStream_t stream) {
  const float* x  = (const float*)d_in[0];
  const float* xr = (const float*)d_in[1];
  float* bm  = (float*)d_ws;          // 512 floats = 2 KB scratch
  float* out = (float*)d_out;

  patch_loss_kernel<<<512, 512, 0, stream>>>(x, xr, bm, out);
}

// Round 4
// 205.964 us; speedup vs baseline: 1.1025x; 1.1025x over previous
//
#include <hip/hip_runtime.h>
#include <math.h>

// x, x_r: (1, 3, 32, 512, 512) fp32. size=64 -> hc=wc=32, nh=nw=16.
// P[t,ph,pw] = mean over (c=3, 32x32) of |x - x_r|/2   (3072 elems/patch)
// out = log( mean_t( max(0, max_{ph,pw} P) ) )  -- scalar fp32.
//
// Round 11 (resubmit; round 12 was an infra failure, no data): explicit
//   24-deep rolling load pipeline on the R8 base.
//   R10 post-mortem: VGPR_Count=32 -> compiler kept ~2 loads in flight ->
//   2.8 TB/s. R9: waves don't help (16==32 waves/CU). Model: read BW =
//   inflight_bytes / latency; need ~6 KB/CU = 24 loads x 16B x 16 waves.
//   So: same R8 partition (1024 blk x 256 thr, block b owns 3 contiguous
//   2048-f4 chunks, 48 nt loads/thread, bin=(tid&127)>>3, part[] +
//   separate finalize — all measured-good), but the 48 loads are now a
//   hand-rolled software pipeline: prologue issues 12 (a,c) pairs; each
//   consume step re-issues one pair into the just-freed registers
//   (constant indices after full unroll -> stays in VGPRs, rule #20).
//   __launch_bounds__(256,4) caps VGPR at 128: 96 data regs + addr fits,
//   16 waves/CU preserved; steady-state ~24 loads in flight per wave.
// Kernel 2: unchanged R8 finalize (measured ~4 us).

typedef float vf4 __attribute__((ext_vector_type(4)));

__global__ __launch_bounds__(256, 4) void patch_sum_kernel(
    const float* __restrict__ x, const float* __restrict__ xr,
    float* __restrict__ part) {
  const int b   = blockIdx.x;        // 0..1023
  const int tid = threadIdx.x;       // 0..255
  const size_t base4 = (size_t)b * 3 * 2048;
  const vf4* __restrict__ a4 = (const vf4*)x  + base4;
  const vf4* __restrict__ c4 = (const vf4*)xr + base4;

  // pair p (0..23): chunk k = p%3, inner i = p/3; offset = k*2048 + i*256 + tid
  // col4 = (i*256+tid) & 127 = tid & 127  ->  pw bin = (tid&127)>>3 constant.
  vf4 A[12], C[12];
  float acc0 = 0.f, acc1 = 0.f, acc2 = 0.f;

#pragma unroll
  for (int p = 0; p < 12; ++p) {
    const int o = (p % 3) * 2048 + (p / 3) * 256 + tid;
    A[p] = __builtin_nontemporal_load(&a4[o]);
    C[p] = __builtin_nontemporal_load(&c4[o]);
  }
#pragma unroll
  for (int p = 0; p < 24; ++p) {
    const int s = p % 12;
    const float d = fabsf(A[s].x - C[s].x) + fabsf(A[s].y - C[s].y)
                  + fabsf(A[s].z - C[s].z) + fabsf(A[s].w - C[s].w);
    if (p < 12) {                      // re-issue into freed registers
      const int q = p + 12;
      const int o = (q % 3) * 2048 + (q / 3) * 256 + tid;
      A[s] = __builtin_nontemporal_load(&a4[o]);
      C[s] = __builtin_nontemporal_load(&c4[o]);
    }
    if (p % 3 == 0) acc0 += d;
    else if (p % 3 == 1) acc1 += d;
    else acc2 += d;
  }

  // 8-lane group reduce for each chunk accumulator (bin = (tid&127)>>3).
#pragma unroll
  for (int o = 4; o > 0; o >>= 1) {
    acc0 += __shfl_down(acc0, o, 8);
    acc1 += __shfl_down(acc1, o, 8);
    acc2 += __shfl_down(acc2, o, 8);
  }
  __shared__ float s[3][32];
  if ((tid & 7) == 0) {
    int m = tid >> 3;                  // 0..31 ; bin = m & 15
    s[0][m] = acc0;
    s[1][m] = acc1;
    s[2][m] = acc2;
  }
  __syncthreads();
  if (tid < 48) {
    int k = tid >> 4;                  // which chunk of the 3
    int bin = tid & 15;                // pw
    part[(size_t)(b * 3 + k) * 16 + bin] = s[k][bin] + s[k][bin + 16];
  }
}

__global__ __launch_bounds__(1024) void finalize_kernel(
    const float* __restrict__ part, float* __restrict__ out) {
  const int tid = threadIdx.x;
  const int t = tid >> 5;             // 0..31
  const int j = tid & 31;
  float m = -1e30f;
#pragma unroll
  for (int k = 0; k < 8; ++k) {
    int p = t * 256 + j + 32 * k;     // patch id within frame t
    int ph = (p >> 4) & 15;
    int pw = p & 15;
    float v = 0.f;
#pragma unroll
    for (int ch = 0; ch < 3; ++ch) {
#pragma unroll
      for (int half = 0; half < 2; ++half) {
        int idx = ((ch << 10) + (t << 5) + (ph << 1) + half) * 16 + pw;
        v += part[idx];
      }
    }
    m = fmaxf(m, v);
  }
#pragma unroll
  for (int o = 16; o > 0; o >>= 1) m = fmaxf(m, __shfl_down(m, o, 32));
  __shared__ float s[32];
  if (j == 0) s[t] = fmaxf(m * (0.5f / 3072.0f), 0.f);  // scale + clamp at 0
  __syncthreads();
  if (tid < 32) {
    float v = s[tid];
#pragma unroll
    for (int o = 16; o > 0; o >>= 1) v += __shfl_down(v, o, 32);
    if (tid == 0) out[0] = logf(v * (1.0f / 32.0f));
  }
}

extern "C" void kernel_launch(void* const* d_in, const int* in_sizes, int n_in,
                              void* d_out, int out_size, void* d_ws, size_t ws_size,
                              hipStream_t stream) {
  const float* x  = (const float*)d_in[0];
  const float* xr = (const float*)d_in[1];
  float* part = (float*)d_ws;        // 3072*16 floats = 192 KB scratch
  float* out  = (float*)d_out;

  patch_sum_kernel<<<1024, 256, 0, stream>>>(x, xr, part);
  finalize_kernel<<<1, 1024, 0, stream>>>(part, out);
}